// Round 5
// baseline (204.293 us; speedup 1.0000x reference)
//
#include <hip/hip_runtime.h>

typedef _Float16 f16;
typedef _Float16 f16x8 __attribute__((ext_vector_type(8)));
typedef float    f32x16 __attribute__((ext_vector_type(16)));

#define NV      2000
#define RR      128
#define KM1     30
#define KKOUT   31
#define NQ      900          // KM1*KM1
#define QQ      961          // KKOUT*KKOUT
#define COV_OFF 62000        // NV*KKOUT
#define NSLOT   576          // total symmetrized k16-slots per q-tile
#define NQT     29           // q-tiles (q = k*30+l < 900)

// ws layout:
//   B2s at 0 : 29 qt x 576 slots x 1024 B = 17,104,896   (f16 frag stream)
//       slot order: i ascending, s in [i>>4, 8); frag = 64 lanes x 16 B,
//       lane(kq,l31) elem d = Bs[(i, j=s*16+kq*8+d), q=qt*32+l31]
//   Xh  [v][r] f16 at 17104896 (524288 B);  Xh2 [r][v] f16 at 17629184
#define B2S_BYTES 17104896
#define XH_BYTES  524288

__device__ __forceinline__ int slot_base(int i) {
    int g = i >> 4, r = i & 15;
    return 16 * (8 * g - (g * (g - 1)) / 2) + r * (8 - g);
}

// prep block-role ranges
#define PERM_BLKS  3840
#define XC1_BLKS   128
#define XC2_BLKS   128
#define ZERO_BLKS  1877
#define MEAN_BLKS  248
#define PREP_GRID  (PERM_BLKS + XC1_BLKS + XC2_BLKS + ZERO_BLKS + MEAN_BLKS)

// ---------------------------------------------------------------------------
// Fused prep. Roles by blockIdx range:
//  [0,3840): symmetrize+permute. Block (i,k): rowS[(j-j0)*30+l] =
//      (j>i: C[(i,k),(j,l)]+C[(j,k),(i,l)]; j==i: C; j<i: 0), then write
//      f16 frag stream. j0 = (i>>4)*16.
//  then: Xh cast, Xh2 cast, zero cov + 0.5 diag, exact fp32 mean.
// ---------------------------------------------------------------------------
__global__ void prep_kernel(const float* __restrict__ Xi,
                            const float* __restrict__ Wm,
                            const float* __restrict__ cov,
                            const float* __restrict__ Cmu,
                            f16* __restrict__ B2s,
                            f16* __restrict__ Xh,
                            f16* __restrict__ Xh2,
                            float* __restrict__ outm,
                            float* __restrict__ oc) {
    __shared__ float rowS[3840];
    int b = blockIdx.x;
    int tid = threadIdx.x;
    if (b < PERM_BLKS) {
        int i = b / 30, k = b - i * 30;
        int j0 = (i >> 4) << 4;
        int W = 128 - j0;
        int lo = (i - j0) * 30;                   // rowS[0,lo) = 0 (pad)
        const float* src = cov + (size_t)b * 3840 + j0 * 30;
        for (int t = tid; t < W * 30; t += 256)
            rowS[t] = (t >= lo) ? src[t] : 0.f;
        __syncthreads();
        // val2: rowS[(j-j0)*30+l] += C[(j*30+k), (i*30+l)], j in (i,128)
        int n2 = (127 - i) * 30;
        for (int idx = tid; idx < n2; idx += 256) {
            int j = i + 1 + idx / 30;
            int l = idx - (j - i - 1) * 30;
            rowS[(j - j0) * 30 + l] += cov[(size_t)(j * 30 + k) * 3840 + i * 30 + l];
        }
        __syncthreads();
        int base_i = slot_base(i);
        int nOct = W >> 3;
        for (int it = tid; it < nOct * 30; it += 256) {
            int oct = it / 30, l = it - oct * 30;
            int j = j0 + oct * 8;
            int s = j >> 4, kq = (j >> 3) & 1;
            int q = k * 30 + l, qt = q >> 5, l31 = q & 31;
            int slot = base_i + s - (i >> 4);
            f16* dst = B2s + (((size_t)qt * NSLOT + slot) * 64 + kq * 32 + l31) * 8;
            f16 vals[8];
#pragma unroll
            for (int d = 0; d < 8; ++d) vals[d] = (f16)rowS[(j + d - j0) * 30 + l];
            *(uint4*)dst = *(uint4*)vals;
        }
        return;
    }
    b -= PERM_BLKS;
    if (b < XC1_BLKS) {                           // Xh [v][r]
        int t = b * 256 + tid;
        int v = t & 2047, rc = t >> 11;           // rc 0..15
        f16 vals[8];
#pragma unroll
        for (int d = 0; d < 8; ++d) {
            float x = (v < NV) ? Xi[(rc * 8 + d) * NV + v] : 0.f;
            vals[d] = (f16)x;
        }
        *(uint4*)(Xh + (size_t)v * 128 + rc * 8) = *(uint4*)vals;
        return;
    }
    b -= XC1_BLKS;
    if (b < XC2_BLKS) {                           // Xh2 [r][v]
        int t = b * 256 + tid;                    // 32768 = 128 r x 256 v8
        int r = t >> 8, v8 = (t & 255) * 8;
        f16 vals[8];
#pragma unroll
        for (int d = 0; d < 8; ++d) {
            int v = v8 + d;
            vals[d] = (f16)((v < NV) ? Xi[r * NV + v] : 0.f);
        }
        *(uint4*)(Xh2 + (size_t)r * 2048 + v8) = *(uint4*)vals;
        return;
    }
    b -= XC2_BLKS;
    if (b < ZERO_BLKS) {
        size_t idx = ((size_t)b * 256 + tid) * 4;
        if (idx < (size_t)NV * QQ) {
            unsigned rem = (unsigned)(idx % QQ);
            float4 zv;
            zv.x = (rem == 0u)   ? 0.5f : 0.f;
            zv.y = (rem == 960u) ? 0.5f : 0.f;
            zv.z = (rem == 959u) ? 0.5f : 0.f;
            zv.w = (rem == 958u) ? 0.5f : 0.f;
            *(float4*)(oc + idx) = zv;
        }
        return;
    }
    b -= ZERO_BLKS;
    int t2 = b * 256 + tid;
    int c = t2 >> 11, v = t2 & 2047;
    if (v >= NV || c >= KKOUT) return;
    if (c == 0) { outm[(size_t)v * KKOUT] = Cmu[v]; return; }
    float acc = 0.f;
    const float* w = Wm + (c - 1);
#pragma unroll 8
    for (int i = 0; i < RR; ++i)
        acc = fmaf(Xi[i * NV + v], w[i * KM1], acc);
    outm[(size_t)v * KKOUT + c] = acc;
}

// ---------------------------------------------------------------------------
// GEMM stage body: one i (nf = 8-G slots), fm=4 MFMAs per slot.
// ---------------------------------------------------------------------------
template<int G>
__device__ __forceinline__ void do_stage(const f16*& bptr,
                                         const f16x8 (&xj)[4][8],
                                         const f16 (&xi)[4],
                                         f32x16 (&acc)[4]) {
    f16x8 bf[8 - G];
#pragma unroll
    for (int s = G; s < 8; ++s) { bf[s - G] = *(const f16x8*)bptr; bptr += 512; }
    f16x8 xs[4];
#pragma unroll
    for (int fm = 0; fm < 4; ++fm)
#pragma unroll
        for (int d = 0; d < 8; ++d) xs[fm][d] = xi[fm];
#pragma unroll
    for (int s = G; s < 8; ++s)
#pragma unroll
        for (int fm = 0; fm < 4; ++fm) {
            f16x8 af = xs[fm] * xj[fm][s];
            acc[fm] = __builtin_amdgcn_mfma_f32_32x32x16_f16(af, bf[s - G], acc[fm], 0, 0, 0);
        }
}

// ---------------------------------------------------------------------------
// GEMM: out += G_sym(2048 x 9216) @ Bs(9216 x 928used). No LDS, no barriers.
// Block: 4 waves x (128v x 32q) stacked -> 512v x 32q. fm=4: each streamed
// B-frag (1 KB) feeds 4 MFMAs -> VMEM demand 128 B/cyc/CU vs fm=2's 256.
// kz splits the slot stream in ~4 equal parts at i = {19,40,68}.
// Grid 480 (16 dead), swizzled: slice's 4 v-blocks land on one XCD.
// ---------------------------------------------------------------------------
__launch_bounds__(256, 2)
__global__ void gemm4_kernel(const f16* __restrict__ B2s,
                             const f16* __restrict__ Xh,
                             const f16* __restrict__ Xh2,
                             float* __restrict__ out_cov) {
    const int bid = blockIdx.x;
    const int slice = ((bid >> 5) << 3) + (bid & 7);   // 0..119
    if (slice >= NQT * 4) return;
    const int qt = slice >> 2, kz = slice & 3;
    const int ILO[4] = {0, 19, 40, 68};
    const int IHI[4] = {19, 40, 68, 128};
    const int SLO[4] = {0, 149, 288, 432};

    const int tid = threadIdx.x, lane = tid & 63, w = tid >> 6;
    const int l31 = lane & 31, kq = lane >> 5;
    const int v0 = ((bid >> 3) & 3) * 512 + w * 128;
    const int vr = v0 + l31;

    f16x8 xj[4][8];
#pragma unroll
    for (int fm = 0; fm < 4; ++fm)
#pragma unroll
        for (int s = 0; s < 8; ++s)
            xj[fm][s] = *(const f16x8*)(Xh + (size_t)(vr + fm * 32) * 128 + s * 16 + kq * 8);

    const int ilo = ILO[kz], ihi = IHI[kz];
    const f16* bptr = B2s + ((size_t)qt * NSLOT + SLO[kz]) * 512 + lane * 8;

    f32x16 acc[4] = {};
    f16 xi[4], xin[4];
#pragma unroll
    for (int fm = 0; fm < 4; ++fm) xin[fm] = Xh2[(size_t)ilo * 2048 + vr + fm * 32];

    for (int i = ilo; i < ihi; ++i) {
#pragma unroll
        for (int fm = 0; fm < 4; ++fm) xi[fm] = xin[fm];
        int inext = (i + 1 < ihi) ? i + 1 : i;
#pragma unroll
        for (int fm = 0; fm < 4; ++fm) xin[fm] = Xh2[(size_t)inext * 2048 + vr + fm * 32];
        switch (i >> 4) {
            case 0: do_stage<0>(bptr, xj, xi, acc); break;
            case 1: do_stage<1>(bptr, xj, xi, acc); break;
            case 2: do_stage<2>(bptr, xj, xi, acc); break;
            case 3: do_stage<3>(bptr, xj, xi, acc); break;
            case 4: do_stage<4>(bptr, xj, xi, acc); break;
            case 5: do_stage<5>(bptr, xj, xi, acc); break;
            case 6: do_stage<6>(bptr, xj, xi, acc); break;
            default: do_stage<7>(bptr, xj, xi, acc); break;
        }
    }

    // epilogue: C/D col=lane&31 (q), row=4*kq+(reg&3)+8*(reg>>2) (v)
    const int q = qt * 32 + l31;
    if (q >= NQ) return;
    const int kk = q / 30, ll = q - kk * 30;
    float* cb = out_cov + (kk + 1) * KKOUT + (ll + 1);
#pragma unroll
    for (int fm = 0; fm < 4; ++fm) {
        int vb = v0 + fm * 32 + 4 * kq;
#pragma unroll
        for (int r = 0; r < 16; ++r) {
            int v = vb + (r & 3) + 8 * (r >> 2);
            if (v < NV) atomicAdd(cb + (size_t)v * QQ, acc[fm][r]);
        }
    }
}

// ---------------------------------------------------------------------------
extern "C" void kernel_launch(void* const* d_in, const int* in_sizes, int n_in,
                              void* d_out, int out_size, void* d_ws, size_t ws_size,
                              hipStream_t stream) {
    const float* Xi  = (const float*)d_in[0];   // (128, 2000)
    const float* Wm  = (const float*)d_in[1];   // (3840, 1)
    const float* Cov = (const float*)d_in[2];   // (3840, 3840)
    const float* Cmu = (const float*)d_in[3];   // (2000, 1)
    float* out      = (float*)d_out;
    float* out_mean = out;                       // (2000, 31)
    float* out_cov  = out + COV_OFF;             // (2000, 31, 31)
    f16* B2s = (f16*)d_ws;
    f16* Xh  = (f16*)((char*)d_ws + B2S_BYTES);
    f16* Xh2 = (f16*)((char*)d_ws + B2S_BYTES + XH_BYTES);

    prep_kernel <<<PREP_GRID, 256, 0, stream>>>(Xi, Wm, Cov, Cmu, B2s, Xh, Xh2,
                                                out_mean, out_cov);
    gemm4_kernel<<<480, 256, 0, stream>>>(B2s, Xh, Xh2, out_cov);
}

// Round 6
// 171.584 us; speedup vs baseline: 1.1906x; 1.1906x over previous
//
#include <hip/hip_runtime.h>

typedef _Float16 f16;
typedef _Float16 f16x8 __attribute__((ext_vector_type(8)));
typedef float    f32x16 __attribute__((ext_vector_type(16)));

#define NV      2000
#define RR      128
#define KM1     30
#define KKOUT   31
#define NQ      900          // KM1*KM1
#define QQ      961          // KKOUT*KKOUT
#define COV_OFF 62000        // NV*KKOUT

// ws layout:
//   B5 at 0: [qt(29)][kz(4)][stage t(16)][slot(9)][1KB frag] = 17,104,896 B
//     stage (qt,kz,t) holds i_a = kz*16+t (slots 0..7-kz, s=kz..7) then
//     i_b = (7-kz)*16+t (slots 8-kz..8, s=7-kz..7); frag: lane(kq,l31) elem d
//     = Bs[i, j=s*16+kq*8+d, q=qt*32+l31] (f16), zero for j<i, diag 1x.
//   Xh at B5_BYTES: f16 X^T [v 0..2047][r 0..127]
#define B5_BYTES 17104896
#define XH_BYTES 524288

#define PERM_BLKS  3840
#define XC1_BLKS   128
#define ZERO_BLKS  1877
#define MEAN_BLKS  248
#define PREP_GRID  (PERM_BLKS + XC1_BLKS + ZERO_BLKS + MEAN_BLKS)

// ---------------------------------------------------------------------------
// Fused prep: symmetrize+permute Cov -> B5; Xh cast; zero cov + 0.5 diag;
// exact fp32 mean. Roles by blockIdx range.
// ---------------------------------------------------------------------------
__global__ void prep_kernel(const float* __restrict__ Xi,
                            const float* __restrict__ Wm,
                            const float* __restrict__ cov,
                            const float* __restrict__ Cmu,
                            f16* __restrict__ B5,
                            f16* __restrict__ Xh,
                            float* __restrict__ outm,
                            float* __restrict__ oc) {
    __shared__ float rowS[3840];
    int b = blockIdx.x, tid = threadIdx.x;
    if (b < PERM_BLKS) {
        int i = b / 30, k = b - i * 30;
        int g = i >> 4;
        int j0 = g << 4;
        int W = 128 - j0;
        int lo = (i - j0) * 30;                   // rowS[0,lo) = 0 (j<i pad)
        const float* src = cov + (size_t)b * 3840 + j0 * 30;
        for (int t = tid; t < W * 30; t += 256)
            rowS[t] = (t >= lo) ? src[t] : 0.f;
        __syncthreads();
        // symmetrize: rowS[(j-j0)*30+l] += C[(j*30+k),(i*30+l)], j in (i,128)
        int n2 = (127 - i) * 15;                  // float2 pairs
        for (int idx = tid; idx < n2; idx += 256) {
            int j = i + 1 + idx / 15;
            int p = idx - (j - i - 1) * 15;
            const float2 v2 = *(const float2*)(cov + (size_t)(j * 30 + k) * 3840 + i * 30 + 2 * p);
            rowS[(j - j0) * 30 + 2 * p]     += v2.x;
            rowS[(j - j0) * 30 + 2 * p + 1] += v2.y;
        }
        __syncthreads();
        int t_st = i & 15;
        int nOct = W >> 3;
        for (int it = tid; it < nOct * 30; it += 256) {
            int oct = it / 30, l = it - oct * 30;
            int j = j0 + oct * 8;
            int s = j >> 4, kq = (j >> 3) & 1;
            int q = k * 30 + l, qt = q >> 5, l31 = q & 31;
            int kz, slot;
            if (g < 4) { kz = g;     slot = s - g; }
            else       { kz = 7 - g; slot = s + 1; }
            f16 vals[8];
#pragma unroll
            for (int d = 0; d < 8; ++d) vals[d] = (f16)rowS[(j + d - j0) * 30 + l];
            f16* dst = B5 + ((((size_t)(qt * 4 + kz) * 16 + t_st) * 9 + slot) << 9)
                          + (kq * 32 + l31) * 8;
            *(uint4*)dst = *(uint4*)vals;
        }
        return;
    }
    b -= PERM_BLKS;
    if (b < XC1_BLKS) {                           // Xh [v][r]
        int t = b * 256 + tid;
        int v = t & 2047, rc = t >> 11;
        f16 vals[8];
#pragma unroll
        for (int d = 0; d < 8; ++d) {
            float x = (v < NV) ? Xi[(rc * 8 + d) * NV + v] : 0.f;
            vals[d] = (f16)x;
        }
        *(uint4*)(Xh + (size_t)v * 128 + rc * 8) = *(uint4*)vals;
        return;
    }
    b -= XC1_BLKS;
    if (b < ZERO_BLKS) {
        size_t idx = ((size_t)b * 256 + tid) * 4;
        if (idx < (size_t)NV * QQ) {
            unsigned rem = (unsigned)(idx % QQ);
            float4 zv;
            zv.x = (rem == 0u)   ? 0.5f : 0.f;
            zv.y = (rem == 960u) ? 0.5f : 0.f;
            zv.z = (rem == 959u) ? 0.5f : 0.f;
            zv.w = (rem == 958u) ? 0.5f : 0.f;
            *(float4*)(oc + idx) = zv;
        }
        return;
    }
    b -= ZERO_BLKS;
    int t2 = b * 256 + tid;
    int c = t2 >> 11, v = t2 & 2047;
    if (v >= NV || c >= KKOUT) return;
    if (c == 0) { outm[(size_t)v * KKOUT] = Cmu[v]; return; }
    float acc = 0.f;
    const float* w = Wm + (c - 1);
#pragma unroll 8
    for (int i = 0; i < RR; ++i)
        acc = fmaf(Xi[i * NV + v], w[i * KM1], acc);
    outm[(size_t)v * KKOUT + c] = acc;
}

// ---------------------------------------------------------------------------
// async global->LDS, 16B per lane (wave-uniform LDS base + lane*16)
// ---------------------------------------------------------------------------
__device__ __forceinline__ void gl2lds16(const f16* g, f16* l) {
    __builtin_amdgcn_global_load_lds(
        (const __attribute__((address_space(1))) unsigned int*)(const void*)g,
        (__attribute__((address_space(3))) unsigned int*)(void*)l,
        16, 0, 0);
}

// ---------------------------------------------------------------------------
// GEMM body, KZ compile-time. Block: 4 waves x (128v x 32q) = 512v x 32q.
// 16 uniform stages of 9 slots (i_a=KZ*16+t pairs with i_b=(7-KZ)*16+t).
// B staged global->LDS (dbuf, 1 stage ahead), waves read via ds_read; each
// 1KB frag feeds 4 MFMAs (fm=4) -> LDS demand ~128 B/cyc vs VMEM-only 250.
// xi scalars pulled out of resident xj regs via __shfl (no extra arrays).
// ---------------------------------------------------------------------------
template<int KZ>
__device__ __forceinline__ void gemm_body(const f16* __restrict__ B5,
                                          const f16* __restrict__ Xh,
                                          float* __restrict__ out_cov,
                                          int qt, int y, f16* lbuf) {
    constexpr int NA = 8 - KZ, NB = 1 + KZ, NS = 8 - KZ, UB = 7 - 2 * KZ;
    const int tid = threadIdx.x, lane = tid & 63, w = tid >> 6;
    const int l31 = lane & 31, kq = lane >> 5;
    const int v0 = y * 512 + w * 128;
    const int vr = v0 + l31;

    // xj[fm][u]: x[vr+fm*32, (KZ+u)*16 + kq*8 + d]  (covers all slots' s)
    f16x8 xj[4][NS];
#pragma unroll
    for (int fm = 0; fm < 4; ++fm)
#pragma unroll
        for (int u = 0; u < NS; ++u)
            xj[fm][u] = *(const f16x8*)(Xh + (size_t)(vr + fm * 32) * 128 + (KZ + u) * 16 + kq * 8);

    const f16* gbase = B5 + ((size_t)(qt * 4 + KZ) * 16) * 4608 + lane * 8;

    f32x16 acc[4] = {};

    // preload stage 0 into buffer 0
#pragma unroll
    for (int r = 0; r < 3; ++r) {
        int m = w + 4 * r;
        if (m < 9) gl2lds16(gbase + m * 512, lbuf + m * 512);
    }
    __syncthreads();

#pragma unroll
    for (int t = 0; t < 16; ++t) {
        const int cur = t & 1;
        if (t < 15) {                            // stage t+1 -> other buffer
            const f16* gs = gbase + (size_t)(t + 1) * 4608;
            f16* ls = lbuf + (cur ^ 1) * 4608;
#pragma unroll
            for (int r = 0; r < 3; ++r) {
                int m = w + 4 * r;
                if (m < 9) gl2lds16(gs + m * 512, ls + m * 512);
            }
        }
        // xi broadcasts: i_a = KZ*16+t (from xj[.][0]), i_b = (7-KZ)*16+t (xj[.][UB])
        const int srcl = l31 + ((t >> 3) << 5);
        f16x8 xsA[4], xsB[4];
#pragma unroll
        for (int fm = 0; fm < 4; ++fm) {
            unsigned short ha = __builtin_bit_cast(unsigned short, (f16)xj[fm][0][t & 7]);
            unsigned short hb = __builtin_bit_cast(unsigned short, (f16)xj[fm][UB][t & 7]);
            int pa = __shfl((int)ha, srcl, 64);
            int pb = __shfl((int)hb, srcl, 64);
            f16 xa = __builtin_bit_cast(f16, (unsigned short)pa);
            f16 xb = __builtin_bit_cast(f16, (unsigned short)pb);
#pragma unroll
            for (int d = 0; d < 8; ++d) { xsA[fm][d] = xa; xsB[fm][d] = xb; }
        }
        const f16* lb = lbuf + cur * 4608 + lane * 8;
#pragma unroll
        for (int m = 0; m < NA; ++m) {           // role-A slots: s = KZ+m
            f16x8 bf = *(const f16x8*)(lb + m * 512);
#pragma unroll
            for (int fm = 0; fm < 4; ++fm)
                acc[fm] = __builtin_amdgcn_mfma_f32_32x32x16_f16(xsA[fm] * xj[fm][m], bf, acc[fm], 0, 0, 0);
        }
#pragma unroll
        for (int m2 = 0; m2 < NB; ++m2) {        // role-B slots: s = 7-KZ+m2
            f16x8 bf = *(const f16x8*)(lb + (NA + m2) * 512);
#pragma unroll
            for (int fm = 0; fm < 4; ++fm)
                acc[fm] = __builtin_amdgcn_mfma_f32_32x32x16_f16(xsB[fm] * xj[fm][UB + m2], bf, acc[fm], 0, 0, 0);
        }
        __syncthreads();
    }

    // epilogue: C/D col=lane&31 (q), row=4*kq+(reg&3)+8*(reg>>2) (v)
    const int q = qt * 32 + l31;
    if (q >= NQ) return;
    const int kk = q / 30, ll = q - kk * 30;
    float* cb = out_cov + (kk + 1) * KKOUT + (ll + 1);
#pragma unroll
    for (int fm = 0; fm < 4; ++fm) {
        int vb = v0 + fm * 32 + 4 * kq;
#pragma unroll
        for (int r = 0; r < 16; ++r) {
            int v = vb + (r & 3) + 8 * (r >> 2);
            if (v < NV) atomicAdd(cb + (size_t)v * QQ, acc[fm][r]);
        }
    }
}

// ---------------------------------------------------------------------------
// Grid 480 = 120 slices (qt,kz) x 4 y; swizzle: slice's 4 y-blocks share one
// XCD (per-XCD B working set ~2.1 MB -> L2-resident, fetched once).
// ---------------------------------------------------------------------------
__launch_bounds__(256, 2)
__global__ void gemm5_kernel(const f16* __restrict__ B5,
                             const f16* __restrict__ Xh,
                             float* __restrict__ out_cov) {
    __shared__ f16 lbuf[2 * 4608];
    const int bid = blockIdx.x;
    const int xcd = bid & 7, base = bid >> 3;
    const int y = base & 3, s3 = base >> 2;      // s3 0..14
    const int S = s3 * 8 + xcd;                  // slice 0..119
    const int qt = S >> 2, kz = S & 3;
    if (qt >= 29) return;
    switch (kz) {
        case 0:  gemm_body<0>(B5, Xh, out_cov, qt, y, lbuf); break;
        case 1:  gemm_body<1>(B5, Xh, out_cov, qt, y, lbuf); break;
        case 2:  gemm_body<2>(B5, Xh, out_cov, qt, y, lbuf); break;
        default: gemm_body<3>(B5, Xh, out_cov, qt, y, lbuf); break;
    }
}

// ---------------------------------------------------------------------------
extern "C" void kernel_launch(void* const* d_in, const int* in_sizes, int n_in,
                              void* d_out, int out_size, void* d_ws, size_t ws_size,
                              hipStream_t stream) {
    const float* Xi  = (const float*)d_in[0];   // (128, 2000)
    const float* Wm  = (const float*)d_in[1];   // (3840, 1)
    const float* Cov = (const float*)d_in[2];   // (3840, 3840)
    const float* Cmu = (const float*)d_in[3];   // (2000, 1)
    float* out      = (float*)d_out;
    float* out_mean = out;                       // (2000, 31)
    float* out_cov  = out + COV_OFF;             // (2000, 31, 31)
    f16* B5 = (f16*)d_ws;
    f16* Xh = (f16*)((char*)d_ws + B5_BYTES);

    prep_kernel <<<PREP_GRID, 256, 0, stream>>>(Xi, Wm, Cov, Cmu, B5, Xh,
                                                out_mean, out_cov);
    gemm5_kernel<<<480, 256, 0, stream>>>(B5, Xh, out_cov);
}